// Round 14
// baseline (267.174 us; speedup 1.0000x reference)
//
#include <hip/hip_runtime.h>

using f32x4  = __attribute__((ext_vector_type(4))) float;
using bf16x8 = __attribute__((ext_vector_type(8))) __bf16;
using u16x4  = __attribute__((ext_vector_type(4))) unsigned short;

#define BK 64
#define REG_HALF   8192      // ushorts: 128 rows x 64 cols
#define A_OFS      0
#define B_OFS      16384
#define BUF_STRIDE 32768     // one buffer = A(32KB)+B(32KB) = 64 KB

#define BARRIER() __builtin_amdgcn_s_barrier()
#define SGB()     __builtin_amdgcn_sched_barrier(0)
#define SGB_NOMFMA() __builtin_amdgcn_sched_barrier(0x3F7)

__device__ __forceinline__ unsigned short f32_to_bf16_bits(float f) {
    unsigned int u = __builtin_bit_cast(unsigned int, f);
    u = (u + 0x7fffu + ((u >> 16) & 1u)) >> 16;
    return (unsigned short)u;
}

__device__ __forceinline__ void gload_lds16(const void* g, void* l) {
    __builtin_amdgcn_global_load_lds(
        (const __attribute__((address_space(1))) unsigned int*)g,
        (__attribute__((address_space(3))) unsigned int*)l,
        16, 0, 0);
}

// ---------------------------------------------------------------------------
// Fused prep: fake-quant x (exact-f32 math, bf16 store) + W f32->bf16.
// ---------------------------------------------------------------------------
__global__ void prep_kernel(const float* __restrict__ x,
                            const float* __restrict__ W,
                            unsigned short* __restrict__ xq,
                            unsigned short* __restrict__ Wb,
                            int t4x, int t4w) {
    int idx = blockIdx.x * 256 + threadIdx.x;
    if (idx < t4x) {
        f32x4 v = *(const f32x4*)(x + (size_t)idx * 4);
        float am = fmaxf(fmaxf(fabsf(v[0]), fabsf(v[1])),
                         fmaxf(fabsf(v[2]), fabsf(v[3])));
        am = fmaxf(am, __shfl_xor(am, 1));
        am = fmaxf(am, __shfl_xor(am, 2));
        am = fmaxf(am, __shfl_xor(am, 4));
        am = fmaxf(am, __shfl_xor(am, 8));
        float delta = fmaxf(am / 127.0f, 1e-5f);
        u16x4 o;
#pragma unroll
        for (int i = 0; i < 4; ++i) {
            float q = rintf(v[i] / delta);           // round-half-even
            q = fminf(fmaxf(q, -127.0f), 127.0f);
            o[i] = f32_to_bf16_bits(q * delta);
        }
        *(u16x4*)(xq + (size_t)idx * 4) = o;
    } else {
        int j = idx - t4x;
        if (j < t4w) {
            f32x4 v = *(const f32x4*)(W + (size_t)j * 4);
            u16x4 o;
#pragma unroll
            for (int i = 0; i < 4; ++i) o[i] = f32_to_bf16_bits(v[i]);
            *(u16x4*)(Wb + (size_t)j * 4) = o;
        }
    }
}

__device__ __forceinline__ void mfma_quad(f32x4 (&acc)[8][4], int mo, int no,
    const bf16x8 (&af)[4][2], const bf16x8 (&bf)[2][2]) {
#pragma unroll
    for (int m = 0; m < 4; ++m)
#pragma unroll
        for (int n = 0; n < 2; ++n)
#pragma unroll
            for (int kk = 0; kk < 2; ++kk)
                acc[mo + m][no + n] = __builtin_amdgcn_mfma_f32_16x16x32_bf16(
                    af[m][kk], bf[n][kk], acc[mo + m][no + n], 0, 0, 0);
}

// ---------------------------------------------------------------------------
// 256x256 bf16 GEMM (B^T). Round-13 schedule VERBATIM (4 phases, 4 barriers,
// one vmcnt(6)/tile, rotation bfA pair, stage stream P1:A-h1(t+1)->nb,
// P2:B-h0(t+2)->cb, P3:A-h0(t+2)->cb, P4:B-h1(t+2)->cb — full RAW/WAR/vmcnt
// ledger in round-13 notes, unchanged). ONLY change: addressing.
//  * 8 hoisted per-lane LDS base pointers ({c,n}buf x {A,B} x {kk0,kk1});
//    all 24 fragment reads are base + compile-time byte offset (<=22528 <
//    65536) -> pure ds_read_b128 with offset:, zero per-read VALU.
//  * staging source = wave-uniform (Ag+tk) [SALU] + per-lane 32-bit offset
//    -> saddr-form global_load_lds, no per-call 64-bit VALU adds.
// ---------------------------------------------------------------------------
__global__ __launch_bounds__(512, 2) void gemm_kernel(
    const unsigned short* __restrict__ A,   // [M][K] bf16 bits (quantized x)
    const unsigned short* __restrict__ B,   // [N][K] bf16 bits (W)
    const float* __restrict__ bias,         // [N]
    float* __restrict__ out,                // [M][N] f32
    int M, int N, int K)
{
    __shared__ unsigned short lds[2 * BUF_STRIDE];   // 128 KiB

    const int tid  = threadIdx.x;
    const int lane = tid & 63;
    const int wv   = tid >> 6;
    const int wm   = wv >> 2;        // 0..1  (128 rows each)
    const int wn   = wv & 3;         // 0..3  (64 cols each)
    const int lr   = lane & 15;
    const int lk   = lane >> 4;      // 0..3
    const int sx   = lr & 7;

    const int nbn = N / 256;
    const int nwg = gridDim.x;
    const int cpx = nwg >> 3;        // bijective XCD swizzle (nwg % 8 == 0)
    const int swz = (blockIdx.x & 7) * cpx + (blockIdx.x >> 3);
    const int bm0 = (swz / nbn) * 256;
    const int bn0 = (swz % nbn) * 256;

    const unsigned short* Ag = A + (size_t)bm0 * K;
    const unsigned short* Bg = B + (size_t)bn0 * K;
    const int NT = K / BK;           // 64, even

    // Hoisted per-lane staging offsets (element units, 32-bit safe).
    const int gr0 = tid >> 3,         gr1 = (512 + tid) >> 3;
    const int c0  = ((tid & 7) ^ (gr0 & 7)) << 3;
    const int c1  = ((tid & 7) ^ (gr1 & 7)) << 3;
    const int offA0 = ((((gr0 >> 6) << 7) + (gr0 & 63))) * K + c0;
    const int offA1 = ((((gr1 >> 6) << 7) + (gr1 & 63))) * K + c1;
    const int offB0 = ((((gr0 >> 5) << 6) + (gr0 & 31))) * K + c0;
    const int offB1 = ((((gr1 >> 5) << 6) + (gr1 & 31))) * K + c1;
    const int ldsu0 = tid * 8, ldsu1 = (512 + tid) * 8;

    // 8 hoisted per-lane LDS read base pointers (elements).
    const int aRow = (wm * 64 + lr) * 64;
    const int bRow = (wn * 32 + lr) * 64;
    const int x0   = (lk ^ sx) << 3;
    const int x1   = ((4 + lk) ^ sx) << 3;
    const unsigned short* pAc0 = lds + A_OFS + aRow + x0;
    const unsigned short* pAc1 = lds + A_OFS + aRow + x1;
    const unsigned short* pBc0 = lds + B_OFS + bRow + x0;
    const unsigned short* pBc1 = lds + B_OFS + bRow + x1;
    const unsigned short* pAn0 = pAc0 + BUF_STRIDE;
    const unsigned short* pAn1 = pAc1 + BUF_STRIDE;
    const unsigned short* pBn0 = pBc0 + BUF_STRIDE;
    const unsigned short* pBn1 = pBc1 + BUF_STRIDE;

#define RD(P, OFS) (*(const bf16x8*)((P) + (OFS)))
// afL: rows m*16 -> +m*1024 ; afH: +8192 ; bfB: +8192+n*1024 ; bfA: +n*1024
#define READ_AF(D, P0, P1, H)                                                  \
    { _Pragma("unroll") for (int m = 0; m < 4; ++m) {                          \
        D[m][0] = RD(P0, (H) + m * 1024); D[m][1] = RD(P1, (H) + m * 1024); } }
#define READ_BF(D, P0, P1, H)                                                  \
    { _Pragma("unroll") for (int n = 0; n < 2; ++n) {                          \
        D[n][0] = RD(P0, (H) + n * 1024); D[n][1] = RD(P1, (H) + n * 1024); } }

#define STAGE_AH0(GT, DST) { gload_lds16((GT) + offA0, (DST) + ldsu0); \
                             gload_lds16((GT) + offA1, (DST) + ldsu1); }
#define STAGE_AH1(GT, DST) { gload_lds16((GT) + 64*K + offA0, (DST) + ldsu0); \
                             gload_lds16((GT) + 64*K + offA1, (DST) + ldsu1); }
#define STAGE_BH0(GT, DST) { gload_lds16((GT) + offB0, (DST) + ldsu0); \
                             gload_lds16((GT) + offB1, (DST) + ldsu1); }
#define STAGE_BH1(GT, DST) { gload_lds16((GT) + 32*K + offB0, (DST) + ldsu0); \
                             gload_lds16((GT) + 32*K + offB1, (DST) + ldsu1); }

    f32x4 acc[8][4] = {};

    // Prologue, ledger call order c1..c7 (oldest first) — same as r13:
    STAGE_AH0(Ag,      lds + A_OFS);                          // c1 A-h0(0)
    STAGE_BH0(Bg,      lds + B_OFS);                          // c2 B-h0(0)
    STAGE_BH1(Bg,      lds + B_OFS + REG_HALF);               // c3 B-h1(0)
    STAGE_AH1(Ag,      lds + A_OFS + REG_HALF);               // c4 A-h1(0)
    STAGE_AH0(Ag + BK, lds + BUF_STRIDE + A_OFS);             // c5 A-h0(1)
    STAGE_BH0(Bg + BK, lds + BUF_STRIDE + B_OFS);             // c6 B-h0(1)
    STAGE_BH1(Bg + BK, lds + BUF_STRIDE + B_OFS + REG_HALF);  // c7 B-h1(1)
    asm volatile("s_waitcnt vmcnt(6)" ::: "memory");          // c1..c4 proven
    SGB();
    BARRIER();

    bf16x8 bfA_e[2][2], bfA_o[2][2];
    READ_BF(bfA_e, pBc0, pBc1, 0);                       // rotation bfA(0)
    asm volatile("s_waitcnt lgkmcnt(0)" ::: "memory");   // delivered
    SGB();
    BARRIER();                                           // plays B((t-1).P4)

#define TILE_ITER(T, PA0, PA1, PB0, PB1, QB0, QB1, BFA_IN, BFA_OUT)            \
    {                                                                          \
        unsigned short* cb_ = (unsigned short*)((PA0) - (aRow + x0) - A_OFS);  \
        unsigned short* nb_ = (unsigned short*)((QB0) - (bRow + x0) - B_OFS);  \
        const unsigned short* AgT1 = Ag + (((T) + 1 < NT) ? (T) + 1 : NT - 1) * BK; \
        const unsigned short* AgT2 = Ag + (((T) + 2 < NT) ? (T) + 2 : NT - 1) * BK; \
        const unsigned short* BgT2 = Bg + (((T) + 2 < NT) ? (T) + 2 : NT - 1) * BK; \
        bf16x8 afL_[4][2], afH_[4][2], bfB_[2][2];                             \
        /* P1: Q1 = afL x bfA_in ; stage A-h1(t+1)->nb */                      \
        READ_AF(afL_, PA0, PA1, 0);                                            \
        STAGE_AH1(AgT1, nb_ + A_OFS + REG_HALF);                               \
        SGB(); BARRIER();                                                      \
        __builtin_amdgcn_s_setprio(1);                                         \
        mfma_quad(acc, 0, 0, afL_, BFA_IN);                                    \
        __builtin_amdgcn_s_setprio(0); SGB_NOMFMA();                           \
        /* P2: Q2 = afL x bfB ; stage B-h0(t+2)->cb */                         \
        READ_BF(bfB_, PB0, PB1, REG_HALF);                                     \
        STAGE_BH0(BgT2, cb_ + B_OFS);                                          \
        SGB(); BARRIER();                                                      \
        __builtin_amdgcn_s_setprio(1);                                         \
        mfma_quad(acc, 0, 2, afL_, bfB_);                                      \
        __builtin_amdgcn_s_setprio(0); SGB_NOMFMA();                           \
        /* P3: Q3 = afH x bfA_in ; stage A-h0(t+2)->cb */                      \
        READ_AF(afH_, PA0, PA1, REG_HALF);                                     \
        STAGE_AH0(AgT2, cb_ + A_OFS);                                          \
        SGB(); BARRIER();                                                      \
        __builtin_amdgcn_s_setprio(1);                                         \
        mfma_quad(acc, 4, 0, afH_, BFA_IN);                                    \
        __builtin_amdgcn_s_setprio(0); SGB_NOMFMA();                           \
        /* P4: stage B-h1(t+2)->cb ; single tile wait ; rotation read */       \
        STAGE_BH1(BgT2, cb_ + B_OFS + REG_HALF);                               \
        asm volatile("s_waitcnt vmcnt(6)" ::: "memory");                       \
        SGB(); BARRIER();                                                      \
        READ_BF(BFA_OUT, QB0, QB1, 0);                                         \
        __builtin_amdgcn_s_setprio(1);                                         \
        mfma_quad(acc, 4, 2, afH_, bfB_);                                      \
        __builtin_amdgcn_s_setprio(0);                                         \
        asm volatile("s_waitcnt lgkmcnt(0)" ::: "memory");                     \
        SGB();                                                                 \
    }

    for (int tt = 0; tt < NT; tt += 2) {
        TILE_ITER(tt,     pAc0, pAc1, pBc0, pBc1, pBn0, pBn1, bfA_e, bfA_o);
        TILE_ITER(tt + 1, pAn0, pAn1, pBn0, pBn1, pBc0, pBc1, bfA_o, bfA_e);
    }
#undef TILE_ITER
#undef STAGE_AH0
#undef STAGE_AH1
#undef STAGE_BH0
#undef STAGE_BH1
#undef READ_AF
#undef READ_BF
#undef RD

    asm volatile("s_waitcnt vmcnt(0) lgkmcnt(0)" ::: "memory"); // drain DMA
    BARRIER();

    // Epilogue: C/D layout col = lane&15, row = (lane>>4)*4 + j  [m89]
    const int r0   = bm0 + wm * 128;
    const int cC0  = bn0 + wn * 64;
    const int rsub = lk << 2;
#pragma unroll
    for (int nf = 0; nf < 4; ++nf) {
        int col = cC0 + nf * 16 + lr;
        float bv = bias[col];
#pragma unroll
        for (int mf = 0; mf < 8; ++mf) {
            int row = r0 + mf * 16 + rsub;
#pragma unroll
            for (int j = 0; j < 4; ++j)
                out[(size_t)(row + j) * N + col] = acc[mf][nf][j] + bv;
        }
    }
}

extern "C" void kernel_launch(void* const* d_in, const int* in_sizes, int n_in,
                              void* d_out, int out_size, void* d_ws, size_t ws_size,
                              hipStream_t stream) {
    const float* x = (const float*)d_in[0];   // [M][K] f32
    const float* W = (const float*)d_in[1];   // [N][K] f32
    const float* b = (const float*)d_in[2];   // [N]   f32
    float* out = (float*)d_out;               // [M][N] f32

    const int N = in_sizes[2];                // 4096
    const int K = in_sizes[1] / N;            // 4096
    const int M = in_sizes[0] / K;            // 8192

    unsigned short* xq = (unsigned short*)d_ws;            // 64 MB
    unsigned short* Wb = xq + (size_t)M * K;               // 32 MB

    const int t4x = (int)(((long long)M * K) / 4);
    const int t4w = (int)(((long long)N * K) / 4);
    prep_kernel<<<(t4x + t4w + 255) / 256, 256, 0, stream>>>(x, W, xq, Wb, t4x, t4w);

    dim3 grid((M / 256) * (N / 256));         // 512 blocks
    gemm_kernel<<<grid, 512, 0, stream>>>(xq, Wb, b, out, M, N, K);
}

// Round 15
// 259.833 us; speedup vs baseline: 1.0283x; 1.0283x over previous
//
#include <hip/hip_runtime.h>

using f32x4  = __attribute__((ext_vector_type(4))) float;
using bf16x8 = __attribute__((ext_vector_type(8))) __bf16;
using u16x4  = __attribute__((ext_vector_type(4))) unsigned short;

#define BK 64
#define REG_HALF   8192      // ushorts: 128 rows x 64 cols
#define A_OFS      0
#define B_OFS      16384
#define BUF_STRIDE 32768     // one buffer = A(32KB)+B(32KB) = 64 KB

#define BARRIER() __builtin_amdgcn_s_barrier()
#define SGB()     __builtin_amdgcn_sched_barrier(0)
#define SGB_NOMFMA() __builtin_amdgcn_sched_barrier(0x3F7)

__device__ __forceinline__ unsigned short f32_to_bf16_bits(float f) {
    unsigned int u = __builtin_bit_cast(unsigned int, f);
    u = (u + 0x7fffu + ((u >> 16) & 1u)) >> 16;
    return (unsigned short)u;
}

__device__ __forceinline__ void gload_lds16(const void* g, void* l) {
    __builtin_amdgcn_global_load_lds(
        (const __attribute__((address_space(1))) unsigned int*)g,
        (__attribute__((address_space(3))) unsigned int*)l,
        16, 0, 0);
}

// ---------------------------------------------------------------------------
// Fused prep: fake-quant x (exact-f32 math, bf16 store) + W f32->bf16.
// ---------------------------------------------------------------------------
__global__ void prep_kernel(const float* __restrict__ x,
                            const float* __restrict__ W,
                            unsigned short* __restrict__ xq,
                            unsigned short* __restrict__ Wb,
                            int t4x, int t4w) {
    int idx = blockIdx.x * 256 + threadIdx.x;
    if (idx < t4x) {
        f32x4 v = *(const f32x4*)(x + (size_t)idx * 4);
        float am = fmaxf(fmaxf(fabsf(v[0]), fabsf(v[1])),
                         fmaxf(fabsf(v[2]), fabsf(v[3])));
        am = fmaxf(am, __shfl_xor(am, 1));
        am = fmaxf(am, __shfl_xor(am, 2));
        am = fmaxf(am, __shfl_xor(am, 4));
        am = fmaxf(am, __shfl_xor(am, 8));
        float delta = fmaxf(am / 127.0f, 1e-5f);
        u16x4 o;
#pragma unroll
        for (int i = 0; i < 4; ++i) {
            float q = rintf(v[i] / delta);           // round-half-even
            q = fminf(fmaxf(q, -127.0f), 127.0f);
            o[i] = f32_to_bf16_bits(q * delta);
        }
        *(u16x4*)(xq + (size_t)idx * 4) = o;
    } else {
        int j = idx - t4x;
        if (j < t4w) {
            f32x4 v = *(const f32x4*)(W + (size_t)j * 4);
            u16x4 o;
#pragma unroll
            for (int i = 0; i < 4; ++i) o[i] = f32_to_bf16_bits(v[i]);
            *(u16x4*)(Wb + (size_t)j * 4) = o;
        }
    }
}

// Fragment readers (region base pointer; T2-swizzled column) ---------------
__device__ __forceinline__ void read_af(bf16x8 (&dst)[4][2],
    const unsigned short* reg, int wm, int lr, int lk, int sx) {
#pragma unroll
    for (int m = 0; m < 4; ++m)
#pragma unroll
        for (int kk = 0; kk < 2; ++kk)
            dst[m][kk] = *(const bf16x8*)(reg
                + (wm * 64 + m * 16 + lr) * 64 + ((((kk << 2) + lk) ^ sx) << 3));
}

__device__ __forceinline__ void read_bf(bf16x8 (&dst)[2][2],
    const unsigned short* reg, int wn, int lr, int lk, int sx) {
#pragma unroll
    for (int n = 0; n < 2; ++n)
#pragma unroll
        for (int kk = 0; kk < 2; ++kk)
            dst[n][kk] = *(const bf16x8*)(reg
                + (wn * 32 + n * 16 + lr) * 64 + ((((kk << 2) + lk) ^ sx) << 3));
}

// Operand-SWAPPED quad: mfma(bf, af) -> D-fragment transposed:
// lane&15 = M-row within m-frag, (lane>>4)*4+j = N-col within n-frag.
// Same products, same f32 accumulation datapath -> numerically identical.
__device__ __forceinline__ void mfma_quad(f32x4 (&acc)[8][4], int mo, int no,
    const bf16x8 (&af)[4][2], const bf16x8 (&bf)[2][2]) {
#pragma unroll
    for (int m = 0; m < 4; ++m)
#pragma unroll
        for (int n = 0; n < 2; ++n)
#pragma unroll
            for (int kk = 0; kk < 2; ++kk)
                acc[mo + m][no + n] = __builtin_amdgcn_mfma_f32_16x16x32_bf16(
                    bf[n][kk], af[m][kk], acc[mo + m][no + n], 0, 0, 0);
}

// ---------------------------------------------------------------------------
// 256x256 bf16 GEMM (B^T). Round-13 schedule VERBATIM (4 phases, 4 barriers,
// one vmcnt(6)/tile, rotation bfA pair, stage stream P1:A-h1(t+1)->nb,
// P2:B-h0(t+2)->cb, P3:A-h0(t+2)->cb, P4:B-h1(t+2)->cb; full RAW/WAR/vmcnt
// ledger unchanged from round 13). ONLY change: operand-swapped MFMA ->
// transposed D-fragment -> epilogue is 32 global_store_dwordx4 per thread
// (each wave-store: 16 rows x 64B contiguous) + dwordx4 bias loads,
// replacing 128 scattered dword stores.
// ---------------------------------------------------------------------------
__global__ __launch_bounds__(512, 2) void gemm_kernel(
    const unsigned short* __restrict__ A,   // [M][K] bf16 bits (quantized x)
    const unsigned short* __restrict__ B,   // [N][K] bf16 bits (W)
    const float* __restrict__ bias,         // [N]
    float* __restrict__ out,                // [M][N] f32
    int M, int N, int K)
{
    __shared__ unsigned short lds[2 * BUF_STRIDE];   // 128 KiB

    const int tid  = threadIdx.x;
    const int lane = tid & 63;
    const int wv   = tid >> 6;
    const int wm   = wv >> 2;        // 0..1  (128 rows each)
    const int wn   = wv & 3;         // 0..3  (64 cols each)
    const int lr   = lane & 15;
    const int lk   = lane >> 4;      // 0..3
    const int sx   = lr & 7;

    const int nbn = N / 256;
    const int nwg = gridDim.x;
    const int cpx = nwg >> 3;        // bijective XCD swizzle (nwg % 8 == 0)
    const int swz = (blockIdx.x & 7) * cpx + (blockIdx.x >> 3);
    const int bm0 = (swz / nbn) * 256;
    const int bn0 = (swz % nbn) * 256;

    const unsigned short* Ag = A + (size_t)bm0 * K;
    const unsigned short* Bg = B + (size_t)bn0 * K;
    const int NT = K / BK;           // 64, even

    // Hoisted per-lane staging offsets (element units, 32-bit safe).
    const int gr0 = tid >> 3,         gr1 = (512 + tid) >> 3;
    const int c0  = ((tid & 7) ^ (gr0 & 7)) << 3;
    const int c1  = ((tid & 7) ^ (gr1 & 7)) << 3;
    const int offA0 = ((((gr0 >> 6) << 7) + (gr0 & 63))) * K + c0;
    const int offA1 = ((((gr1 >> 6) << 7) + (gr1 & 63))) * K + c1;
    const int offB0 = ((((gr0 >> 5) << 6) + (gr0 & 31))) * K + c0;
    const int offB1 = ((((gr1 >> 5) << 6) + (gr1 & 31))) * K + c1;
    const int ldsu0 = tid * 8, ldsu1 = (512 + tid) * 8;

#define STAGE_AH0(TK, DST) { gload_lds16(Ag + offA0 + (TK), (DST) + ldsu0); \
                             gload_lds16(Ag + offA1 + (TK), (DST) + ldsu1); }
#define STAGE_AH1(TK, DST) { gload_lds16(Ag + offA0 + 64*K + (TK), (DST) + ldsu0); \
                             gload_lds16(Ag + offA1 + 64*K + (TK), (DST) + ldsu1); }
#define STAGE_BH0(TK, DST) { gload_lds16(Bg + offB0 + (TK), (DST) + ldsu0); \
                             gload_lds16(Bg + offB1 + (TK), (DST) + ldsu1); }
#define STAGE_BH1(TK, DST) { gload_lds16(Bg + offB0 + 32*K + (TK), (DST) + ldsu0); \
                             gload_lds16(Bg + offB1 + 32*K + (TK), (DST) + ldsu1); }

    f32x4 acc[8][4] = {};

    // Prologue, ledger call order c1..c7 (oldest first):
    STAGE_AH0(0,  lds + A_OFS);                          // c1 A-h0(0)
    STAGE_BH0(0,  lds + B_OFS);                          // c2 B-h0(0)
    STAGE_BH1(0,  lds + B_OFS + REG_HALF);               // c3 B-h1(0)
    STAGE_AH1(0,  lds + A_OFS + REG_HALF);               // c4 A-h1(0)
    STAGE_AH0(BK, lds + BUF_STRIDE + A_OFS);             // c5 A-h0(1)
    STAGE_BH0(BK, lds + BUF_STRIDE + B_OFS);             // c6 B-h0(1)
    STAGE_BH1(BK, lds + BUF_STRIDE + B_OFS + REG_HALF);  // c7 B-h1(1)
    asm volatile("s_waitcnt vmcnt(6)" ::: "memory");     // c1..c4 proven
    SGB();
    BARRIER();

    bf16x8 bfA_e[2][2], bfA_o[2][2];
    read_bf(bfA_e, lds + B_OFS, wn, lr, lk, sx);         // rotation bfA(0)
    asm volatile("s_waitcnt lgkmcnt(0)" ::: "memory");   // delivered
    SGB();
    BARRIER();                                           // plays B((t-1).P4)

#define TILE_ITER(T, CB, NB, BFA_IN, BFA_OUT)                                  \
    {                                                                          \
        unsigned short* cb_ = (CB);                                            \
        unsigned short* nb_ = (NB);                                            \
        const int tk1 = (((T) + 1 < NT) ? (T) + 1 : NT - 1) * BK;              \
        const int tk2 = (((T) + 2 < NT) ? (T) + 2 : NT - 1) * BK;              \
        bf16x8 afL_[4][2], afH_[4][2], bfB_[2][2];                             \
        /* P1: Q1 = afL x bfA_in */                                            \
        read_af(afL_, cb_ + A_OFS, wm, lr, lk, sx);                            \
        STAGE_AH1(tk1, nb_ + A_OFS + REG_HALF);                                \
        SGB(); BARRIER();                                                      \
        __builtin_amdgcn_s_setprio(1);                                         \
        mfma_quad(acc, 0, 0, afL_, BFA_IN);                                    \
        __builtin_amdgcn_s_setprio(0); SGB_NOMFMA();                           \
        /* P2: Q2 = afL x bfB */                                               \
        read_bf(bfB_, cb_ + B_OFS + REG_HALF, wn, lr, lk, sx);                 \
        STAGE_BH0(tk2, cb_ + B_OFS);                                           \
        SGB(); BARRIER();                                                      \
        __builtin_amdgcn_s_setprio(1);                                         \
        mfma_quad(acc, 0, 2, afL_, bfB_);                                      \
        __builtin_amdgcn_s_setprio(0); SGB_NOMFMA();                           \
        /* P3: Q3 = afH x bfA_in */                                            \
        read_af(afH_, cb_ + A_OFS + REG_HALF, wm, lr, lk, sx);                 \
        STAGE_AH0(tk2, cb_ + A_OFS);                                           \
        SGB(); BARRIER();                                                      \
        __builtin_amdgcn_s_setprio(1);                                         \
        mfma_quad(acc, 4, 0, afH_, BFA_IN);                                    \
        __builtin_amdgcn_s_setprio(0); SGB_NOMFMA();                           \
        /* P4: single tile wait; rotation read after its proof barrier */      \
        STAGE_BH1(tk2, cb_ + B_OFS + REG_HALF);                                \
        asm volatile("s_waitcnt vmcnt(6)" ::: "memory");                       \
        SGB(); BARRIER();                                                      \
        read_bf(BFA_OUT, nb_ + B_OFS, wn, lr, lk, sx);                         \
        __builtin_amdgcn_s_setprio(1);                                         \
        mfma_quad(acc, 4, 2, afH_, bfB_);                                      \
        __builtin_amdgcn_s_setprio(0);                                         \
        asm volatile("s_waitcnt lgkmcnt(0)" ::: "memory");                     \
        SGB();                                                                 \
    }

    for (int tt = 0; tt < NT; tt += 2) {
        TILE_ITER(tt,     lds,              lds + BUF_STRIDE, bfA_e, bfA_o);
        TILE_ITER(tt + 1, lds + BUF_STRIDE, lds,              bfA_o, bfA_e);
    }
#undef TILE_ITER
#undef STAGE_AH0
#undef STAGE_AH1
#undef STAGE_BH0
#undef STAGE_BH1

    asm volatile("s_waitcnt vmcnt(0) lgkmcnt(0)" ::: "memory"); // drain DMA
    BARRIER();

    // Epilogue (transposed D-fragment): lane&15 = M-row, (lane>>4)*4+j =
    // N-col. Each acc[mf][nf] is 4 consecutive N-cols at one row ->
    // float4 store. Wave-store = 16 rows x 64 B contiguous.
    const int r0   = bm0 + wm * 128;          // + mf*16 + lr
    const int cC0  = bn0 + wn * 64;           // + nf*16 + (lk<<2)
    const int csub = lk << 2;
#pragma unroll
    for (int nf = 0; nf < 4; ++nf) {
        const int colbase = cC0 + nf * 16 + csub;
        const f32x4 bv = *(const f32x4*)(bias + colbase);
#pragma unroll
        for (int mf = 0; mf < 8; ++mf) {
            const int row = r0 + mf * 16 + lr;
            *(f32x4*)(out + (size_t)row * N + colbase) = acc[mf][nf] + bv;
        }
    }
}

extern "C" void kernel_launch(void* const* d_in, const int* in_sizes, int n_in,
                              void* d_out, int out_size, void* d_ws, size_t ws_size,
                              hipStream_t stream) {
    const float* x = (const float*)d_in[0];   // [M][K] f32
    const float* W = (const float*)d_in[1];   // [N][K] f32
    const float* b = (const float*)d_in[2];   // [N]   f32
    float* out = (float*)d_out;               // [M][N] f32

    const int N = in_sizes[2];                // 4096
    const int K = in_sizes[1] / N;            // 4096
    const int M = in_sizes[0] / K;            // 8192

    unsigned short* xq = (unsigned short*)d_ws;            // 64 MB
    unsigned short* Wb = xq + (size_t)M * K;               // 32 MB

    const int t4x = (int)(((long long)M * K) / 4);
    const int t4w = (int)(((long long)N * K) / 4);
    prep_kernel<<<(t4x + t4w + 255) / 256, 256, 0, stream>>>(x, W, xq, Wb, t4x, t4w);

    dim3 grid((M / 256) * (N / 256));         // 512 blocks
    gemm_kernel<<<grid, 512, 0, stream>>>(xq, Wb, b, out, M, N, K);
}